// Round 7
// baseline (89.836 us; speedup 1.0000x reference)
//
#include <hip/hip_runtime.h>
#include <math.h>

// KDE, dot-product form: sqd = ||x||^2 + ||t||^2 - 2 x.t
// exp(-sqd/(2*var)) = exp2(EXP2_SCALE*sqd), var=0.04^2, 2var=0.0032
//
// R7: single-pass main (no prep, no atomics, no zero kernel).
//  - lane = test point; its 64-dim test vector lives in VGPRs, loaded once
//    directly from `test` (4x float4, one-time scatter), ||x||^2 in-register.
//  - train rows are wave-uniform -> scalar s_load_dwordx16 through K$.
//  - chunk norms computed cooperatively per block: one fully-coalesced float4
//    pass over the 4 KB chunk -> LDS partials -> 16 row norms. Inner loop
//    stays pure dot-form: 64 v_fma + v_exp per row. (R6 lesson: NO uniform
//    ds_read in the hot loop - 16 B / 12 cyc starves the LDS pipe.)
//  - block (tg,chunk) writes partial sums to ws[chunk][ti] (coalesced store);
//    kde_reduce sums 256 partials per output and applies MEAN_SCALE,
//    overwriting d_out poison (no zeroing needed anywhere).

#define D          64
#define N_TRAIN    4096
#define N_TEST     1024
#define ROWS       16                       // train rows per chunk
#define CHUNKS     (N_TRAIN / ROWS)         // 256
#define EXP2_SCALE (-450.84220027780106f)   // -log2(e)/0.0032
#define NEG2SCALE  (901.6844005556021f)     // -2*EXP2_SCALE
#define COEF       (9.973557010035818f)     // 1/sqrt(2*pi*var)
#define MEAN_SCALE (COEF / 4096.0f)

__global__ __launch_bounds__(256) void kde_main(
    const float* __restrict__ test,
    const float* __restrict__ train,
    float* __restrict__ part)
{
    __shared__ float pn[ROWS][17];          // padded: norm partials
    __shared__ float snorm[ROWS];           // EXP2_SCALE * ||t_row||^2

    const int t     = threadIdx.x;
    const int lane  = t & 63;
    const int wv    = t >> 6;
    const int tg    = blockIdx.x & 3;       // test group (256 tests)
    const int chunk = blockIdx.x >> 2;      // train chunk (16 rows)
    const int ti    = tg * 256 + wv * 64 + lane;
    const int j0    = chunk * ROWS;

    // Cooperative row-norm partials: thread = (row, 4-dim slice), coalesced.
    {
        const int r = t >> 4, c = t & 15;
        float4 v = ((const float4*)(train + (size_t)(j0 + r) * D))[c];
        pn[r][c] = v.x * v.x + v.y * v.y + v.z * v.z + v.w * v.w;
    }

    // Per-lane test vector into VGPRs (one-time) + ||x||^2.
    float x[D];
    float n0 = 0.f, n1 = 0.f, n2 = 0.f, n3 = 0.f;
    {
        const float4* xp = (const float4*)(test + (size_t)ti * D);
        #pragma unroll
        for (int c = 0; c < D / 4; ++c) {
            float4 v = xp[c];
            x[4*c+0] = v.x; x[4*c+1] = v.y; x[4*c+2] = v.z; x[4*c+3] = v.w;
            n0 = fmaf(v.x, v.x, n0); n1 = fmaf(v.y, v.y, n1);
            n2 = fmaf(v.z, v.z, n2); n3 = fmaf(v.w, v.w, n3);
        }
    }
    const float xs = ((n0 + n1) + (n2 + n3)) * EXP2_SCALE;

    __syncthreads();
    if (t < ROWS) {
        float s = 0.f;
        #pragma unroll
        for (int i = 0; i < 16; ++i) s += pn[t][i];
        snorm[t] = s * EXP2_SCALE;
    }
    __syncthreads();

    float sum = 0.0f;
    for (int jj = 0; jj < ROWS; ++jj) {
        const float* __restrict__ trow = train + (size_t)(j0 + jj) * D;
        float d0 = 0.f, d1 = 0.f, d2 = 0.f, d3 = 0.f;
        #pragma unroll
        for (int c = 0; c < D / 4; ++c) {
            float4 tv = ((const float4*)trow)[c];   // uniform -> s_load
            d0 = fmaf(tv.x, x[4*c+0], d0);
            d1 = fmaf(tv.y, x[4*c+1], d1);
            d2 = fmaf(tv.z, x[4*c+2], d2);
            d3 = fmaf(tv.w, x[4*c+3], d3);
        }
        const float dot = (d0 + d1) + (d2 + d3);
        sum += exp2f(fmaf(dot, NEG2SCALE, xs + snorm[jj]));
    }

    part[(size_t)chunk * N_TEST + ti] = sum;    // coalesced store
}

__global__ __launch_bounds__(256) void kde_reduce(
    const float* __restrict__ part,
    float* __restrict__ out)
{
    const int ti = blockIdx.x * 256 + threadIdx.x;
    float s0 = 0.f, s1 = 0.f, s2 = 0.f, s3 = 0.f;
    #pragma unroll 4
    for (int c = 0; c < CHUNKS; c += 4) {       // coalesced, independent loads
        s0 += part[(size_t)(c + 0) * N_TEST + ti];
        s1 += part[(size_t)(c + 1) * N_TEST + ti];
        s2 += part[(size_t)(c + 2) * N_TEST + ti];
        s3 += part[(size_t)(c + 3) * N_TEST + ti];
    }
    out[ti] = ((s0 + s1) + (s2 + s3)) * MEAN_SCALE;
}

extern "C" void kernel_launch(void* const* d_in, const int* in_sizes, int n_in,
                              void* d_out, int out_size, void* d_ws, size_t ws_size,
                              hipStream_t stream) {
    const float* test  = (const float*)d_in[0];   // [4,256,64]
    const float* train = (const float*)d_in[1];   // [4096,64]
    float* out  = (float*)d_out;                  // 1024 floats
    float* part = (float*)d_ws;                   // CHUNKS*1024 floats = 1 MB

    kde_main<<<dim3(4 * CHUNKS), dim3(256), 0, stream>>>(test, train, part);
    kde_reduce<<<dim3(N_TEST / 256), dim3(256), 0, stream>>>(part, out);
}